// Round 5
// baseline (150.330 us; speedup 1.0000x reference)
//
#include <hip/hip_runtime.h>
#include <math.h>

#define B_    16
#define T_    512
#define D_    2048
#define DS_   4096
#define TCHUNK 4
#define TCPB   2
#define TSPLIT (T_ / (TCHUNK * TCPB))   // 64 blocks per b
#define EPS_  1e-8f
#define CLOG  34.5f                      // e^-34.5 ~ 1e-15: drop threshold

// ws (floats unless noted):
// num[B_*DS_] | inv_den[DS_] | g_s[DS_] | e4m_s[DS_] | nr_s[DS_]
// | pair_s[DS_] (int) | nout_s[DS_] (int) | hcap_s[DS_] (int)

__device__ __forceinline__ float softplus_f(float x) {
    return (x > 20.f) ? x : log1pf(expf(x));
}

__global__ __launch_bounds__(256) void pre_kernel(const float* __restrict__ decay_rates,
                                                  float* __restrict__ num,
                                                  float* __restrict__ inv_den) {
    int gtid = blockIdx.x * 256 + threadIdx.x;      // 0..65535
    num[gtid] = 0.f;                                // ws is poisoned 0xAA -> zero
    if (gtid < DS_) {
        float r = softplus_f(decay_rates[gtid]);
        // sum_{k=0}^{T-1} e^{-rk} = expm1(-rT)/expm1(-r)
        float S = expm1f(-r * (float)T_) / expm1f(-r);
        inv_den[gtid] = 1.0f / sqrtf(S + EPS_);
    }
}

// Counting sort of n by horizon bucket, DESCENDING horizon.
__global__ __launch_bounds__(1024) void sort_kernel(const float* __restrict__ decay_rates,
                                                    const int* __restrict__ idx_i,
                                                    const int* __restrict__ idx_j,
                                                    float* __restrict__ g_s,
                                                    float* __restrict__ e4m_s,
                                                    float* __restrict__ nr_s,
                                                    int* __restrict__ pair_s,
                                                    int* __restrict__ nout_s,
                                                    int* __restrict__ hcap_s) {
    __shared__ int hist[64];
    const int tid = threadIdx.x;
    if (tid < 64) hist[tid] = 0;
    __syncthreads();
    #pragma unroll
    for (int k = 0; k < 4; ++k) {
        int n = tid + k * 1024;
        float r = softplus_f(decay_rates[n]);
        float hf = CLOG / r;
        int h = (hf >= 511.f) ? 511 : (int)hf;      // max exponent kept (inf-safe)
        atomicAdd(&hist[h >> 3], 1);
    }
    __syncthreads();
    if (tid == 0) {                                  // exclusive scan, descending q
        int run = 0;
        for (int q = 63; q >= 0; --q) { int c = hist[q]; hist[q] = run; run += c; }
    }
    __syncthreads();
    #pragma unroll
    for (int k = 0; k < 4; ++k) {
        int n = tid + k * 1024;
        float r = softplus_f(decay_rates[n]);
        float hf = CLOG / r;
        int h = (hf >= 511.f) ? 511 : (int)hf;
        int q = h >> 3;
        int pos = atomicAdd(&hist[q], 1);
        g_s[pos]    = expf(r);
        e4m_s[pos]  = expf(-4.f * r);
        nr_s[pos]   = -r;
        pair_s[pos] = idx_i[n] | (idx_j[n] << 16);
        nout_s[pos] = n;
        hcap_s[pos] = (q << 3) | 7;                  // conservative upper bound, monotone
    }
}

__global__ __launch_bounds__(256, 4) void main_kernel(const float* __restrict__ z,
                                                      const float* __restrict__ g_s,
                                                      const float* __restrict__ e4m_s,
                                                      const float* __restrict__ nr_s,
                                                      const int* __restrict__ pair_s,
                                                      const int* __restrict__ nout_s,
                                                      const int* __restrict__ hcap_s,
                                                      float* __restrict__ num) {
    __shared__ float4 quads[D_];                     // 32 KB: quad c = rows t0..t0+3 at channel c
    const int tbase = blockIdx.x * (TCHUNK * TCPB);  // 8 t-rows per block
    const int b     = blockIdx.y;
    const int tid   = threadIdx.x;

    // Wave-uniform horizon caps -> SGPRs (lane0's slot has the wave's max hcap).
    int hb[16];
    #pragma unroll
    for (int s = 0; s < 16; ++s)
        hb[s] = __builtin_amdgcn_readfirstlane(hcap_s[tid + s * 256]);

    const int kbW = 504 - tbase;                     // widest kmin (first-processed chunk)
    const int kb1 = 507 - tbase;                     // kbase of first-processed chunk

    float g[16], w0[16], acc[16];
    int pair[16];
    #pragma unroll
    for (int s = 0; s < 16; ++s) {
        acc[s] = 0.f;
        if (hb[s] >= kbW) {                          // only live slots load params
            int m = tid + s * 256;
            pair[s] = pair_s[m];
            g[s]    = g_s[m];
            w0[s]   = __expf(nr_s[m] * (float)kb1);  // exp(-r * kbase_first)
        }
    }

    const float* zb = z + (size_t)b * T_ * D_;
    #pragma unroll 1
    for (int c = TCPB - 1; c >= 0; --c) {            // t descending -> w0 shrinks (stable)
        const int t0 = tbase + c * TCHUNK;
        const float* base = zb + (size_t)t0 * D_;
        #pragma unroll
        for (int it = 0; it < D_ / 256; ++it) {
            int ci = tid + it * 256;
            quads[ci] = make_float4(base[ci], base[D_ + ci],
                                    base[2 * D_ + ci], base[3 * D_ + ci]);
        }
        __syncthreads();
        const int kmin = 508 - t0;                   // smallest exponent in this chunk
        #pragma unroll
        for (int s = 0; s < 16; ++s) {
            if (hb[s] >= kmin) {                     // wave-uniform s_cbranch skip
                int pk = pair[s];
                float4 vi = quads[pk & 0xFFFF];      // one ds_read_b128 = 4 t-rows
                float4 vj = quads[pk >> 16];
                float gs = g[s];
                float h3 = vi.w * vj.w;
                float h2 = fmaf(h3, gs, vi.z * vj.z);
                float h1 = fmaf(h2, gs, vi.y * vj.y);
                float h0 = fmaf(h1, gs, vi.x * vj.x);
                acc[s] = fmaf(w0[s], h0, acc[s]);
                if (c > 0) w0[s] *= e4m_s[tid + s * 256];   // advance kbase by 4
            }
        }
        __syncthreads();
    }
    #pragma unroll
    for (int s = 0; s < 16; ++s)
        if (hb[s] >= kbW && acc[s] != 0.f)
            atomicAdd(&num[b * DS_ + nout_s[tid + s * 256]], acc[s]);
}

__global__ __launch_bounds__(256) void fin_kernel(const float* __restrict__ num,
                                                  const float* __restrict__ inv_den,
                                                  float* __restrict__ out) {
    int gtid = blockIdx.x * 256 + threadIdx.x;
    out[gtid] = num[gtid] * inv_den[gtid & (DS_ - 1)];
}

extern "C" void kernel_launch(void* const* d_in, const int* in_sizes, int n_in,
                              void* d_out, int out_size, void* d_ws, size_t ws_size,
                              hipStream_t stream) {
    const float* z  = (const float*)d_in[0];   // (16,512,2048) f32
    const float* dr = (const float*)d_in[1];   // (4096,) f32
    const int*   ii = (const int*)d_in[2];     // (4096,) i32
    const int*   jj = (const int*)d_in[3];     // (4096,) i32
    float* out = (float*)d_out;                // (16,4096) f32

    float* num     = (float*)d_ws;
    float* inv_den = num + B_ * DS_;
    float* g_s     = inv_den + DS_;
    float* e4m_s   = g_s + DS_;
    float* nr_s    = e4m_s + DS_;
    int*   pair_s  = (int*)(nr_s + DS_);
    int*   nout_s  = pair_s + DS_;
    int*   hcap_s  = nout_s + DS_;

    hipLaunchKernelGGL(pre_kernel, dim3((B_ * DS_) / 256), dim3(256), 0, stream,
                       dr, num, inv_den);
    hipLaunchKernelGGL(sort_kernel, dim3(1), dim3(1024), 0, stream,
                       dr, ii, jj, g_s, e4m_s, nr_s, pair_s, nout_s, hcap_s);
    hipLaunchKernelGGL(main_kernel, dim3(TSPLIT, B_), dim3(256), 0, stream,
                       z, g_s, e4m_s, nr_s, pair_s, nout_s, hcap_s, num);
    hipLaunchKernelGGL(fin_kernel, dim3((B_ * DS_) / 256), dim3(256), 0, stream,
                       num, inv_den, out);
}